// Round 1
// baseline (5356.367 us; speedup 1.0000x reference)
//
#include <hip/hip_runtime.h>
#include <cstdint>
#include <cstddef>

#define BB    128
#define TFRM  80
#define DECL  30
#define EE    512
#define FEATD 4096
#define VV    6000
#define VPAD  6016
#define NBLK  128

using frag_ab = __attribute__((ext_vector_type(8))) short;
using frag_cd = __attribute__((ext_vector_type(4))) float;

static __device__ __forceinline__ float sigf(float x)  { return 1.0f / (1.0f + __expf(-x)); }
static __device__ __forceinline__ float tanhf_(float x){ float e = __expf(2.0f * x); return 1.0f - 2.0f / (e + 1.0f); }
static __device__ __forceinline__ unsigned short f2bf_rne(float x) {
    unsigned int u = __float_as_uint(x);
    u += 0x7fffu + ((u >> 16) & 1u);
    return (unsigned short)(u >> 16);
}

// async global->LDS, 16B per lane. LDS dest must be wave-uniform base + lane*16.
static __device__ __forceinline__ void gl_lds16(const unsigned short* g, unsigned short* l) {
    __builtin_amdgcn_global_load_lds(
        (const __attribute__((address_space(1))) unsigned int*)g,
        (__attribute__((address_space(3))) unsigned int*)l, 16, 0, 0);
}

// device-scope grid barrier: all NBLK blocks co-resident (grid<=CUs, 1 block/CU).
static __device__ __forceinline__ void gridbar(unsigned int* cnt, unsigned int target) {
    __syncthreads();                       // drains each wave's vmcnt before arrival
    if (threadIdx.x == 0) {
        __threadfence();                   // release: L2 writeback (cross-XCD visibility)
        __hip_atomic_fetch_add(cnt, 1u, __ATOMIC_RELAXED, __HIP_MEMORY_SCOPE_AGENT);
        while (__hip_atomic_load(cnt, __ATOMIC_RELAXED, __HIP_MEMORY_SCOPE_AGENT) < target)
            __builtin_amdgcn_s_sleep(1);
        __threadfence();                   // acquire: invalidate stale L1/L2 lines
    }
    __syncthreads();
}

// ---------------- init: zero h ping-pong buffers (bf16), out, barrier counter ----------------
__global__ void init_zero(unsigned int* h1a, unsigned int* h1b, unsigned int* h2a, unsigned int* h2b,
                          float* out, unsigned int* barcnt) {
    int i = blockIdx.x * blockDim.x + threadIdx.x;   // 32768 threads
    h1a[i] = 0u; h1b[i] = 0u; h2a[i] = 0u; h2b[i] = 0u;
    if (i == 0) { out[0] = 0.f; barcnt[0] = 0u; }
}

// ---------------- fp32 -> bf16 (RNE), x4 ----------------
__global__ void f2bf(const float* __restrict__ src, unsigned short* __restrict__ dst, int n4) {
    int i = blockIdx.x * blockDim.x + threadIdx.x;
    if (i >= n4) return;
    float4 v = ((const float4*)src)[i];
    ushort4 o;
    o.x = f2bf_rne(v.x); o.y = f2bf_rne(v.y); o.z = f2bf_rne(v.z); o.w = f2bf_rne(v.w);
    ((ushort4*)dst)[i] = o;
}

// ---------------- build Wcat2 [2048,1024] bf16: cols 0..511 = w_ih2[:,512:], cols 512.. = w_hh2 ----------------
__global__ void build_wcat2(const float* __restrict__ w_ih2, const float* __restrict__ w_hh2,
                            unsigned short* __restrict__ dst, int n4) {
    int i = blockIdx.x * blockDim.x + threadIdx.x;   // n4 = 2048*1024/4
    if (i >= n4) return;
    int r  = i >> 8;              // /256
    int c  = (i & 255) * 4;
    const float* src = (c < 512) ? (w_ih2 + (size_t)r * 1024 + 512 + c)
                                 : (w_hh2 + (size_t)r * 512 + (c - 512));
    float4 v = *(const float4*)src;
    ushort4 o;
    o.x = f2bf_rne(v.x); o.y = f2bf_rne(v.y); o.z = f2bf_rne(v.z); o.w = f2bf_rne(v.w);
    ((ushort4*)dst)[i] = o;
}

// ---------------- w_out -> bf16 padded to 6016 rows (pad rows zero) ----------------
__global__ void wout_pad(const float* __restrict__ w_out, unsigned short* __restrict__ dst, int n4) {
    int i = blockIdx.x * blockDim.x + threadIdx.x;   // n4 = 6016*512/4
    if (i >= n4) return;
    int r = i >> 7;               // /128
    int c = (i & 127) * 4;
    ushort4 o;
    if (r < VV) {
        float4 v = *(const float4*)(w_out + (size_t)r * EE + c);
        o.x = f2bf_rne(v.x); o.y = f2bf_rne(v.y); o.z = f2bf_rne(v.z); o.w = f2bf_rne(v.w);
    } else {
        o.x = 0; o.y = 0; o.z = 0; o.w = 0;
    }
    ((ushort4*)dst)[i] = o;
}

// ---------------- gather decoder word inputs: rows r = b*29+t from caption[b][t][:] (t<29), bf16 ----------------
__global__ void xdec_gather(const float* __restrict__ cap, unsigned short* __restrict__ dst, int n4) {
    int i = blockIdx.x * blockDim.x + threadIdx.x;   // n4 = 3712*512/4
    if (i >= n4) return;
    int row = i >> 7;             // /128
    int c   = (i & 127) * 4;
    int b = row / 29, t = row - b * 29;
    float4 v = *(const float4*)(cap + (size_t)(b * DECL + t) * EE + c);
    ushort4 o;
    o.x = f2bf_rne(v.x); o.y = f2bf_rne(v.y); o.z = f2bf_rne(v.z); o.w = f2bf_rne(v.w);
    ((ushort4*)dst)[i] = o;
}

// ---------------- bias sums ----------------
__global__ void bias_sum(const float* b_ih1, const float* b_hh1, const float* b_ih2, const float* b_hh2,
                         float* bs1, float* bs2) {
    int i = blockIdx.x * blockDim.x + threadIdx.x;   // 2048
    bs1[i] = b_ih1[i] + b_hh1[i];
    bs2[i] = b_ih2[i] + b_hh2[i];
}

// ---------------- argmax over vocab (first-index ties) ----------------
__global__ void argmax_k(const float* __restrict__ oh, int* __restrict__ labels) {
    int row = blockIdx.x;                       // b*DECL + t
    const float* p = oh + (size_t)row * VV;
    int lane = threadIdx.x;
    float best = -1e30f; int bi = 0x7fffffff;
    for (int v = lane; v < VV; v += 64) {
        float x = p[v];
        if (x > best) { best = x; bi = v; }
    }
    for (int off = 32; off; off >>= 1) {
        float ob = __shfl_down(best, off);
        int   oi = __shfl_down(bi,   off);
        if (ob > best || (ob == best && oi < bi)) { best = ob; bi = oi; }
    }
    if (lane == 0) labels[row] = bi;
}

// ---------------- 128x128 bf16 NT GEMM (m97 structure: BK=32, global_load_lds w16) ----------------
// C[M,N](fp32,ldc) = A[M,K](lda) @ B[N,K](ldb)^T ; M%128==0, N%128==0, K%32==0
__global__ __launch_bounds__(256) void gemm128(const unsigned short* __restrict__ A, int lda,
                                               const unsigned short* __restrict__ B, int ldb,
                                               float* __restrict__ C, int ldc,
                                               int K, int ntn) {
    __shared__ unsigned short As[128][32];
    __shared__ unsigned short Bs[128][32];
    int bm = blockIdx.x / ntn, bn = blockIdx.x % ntn;
    int tid = threadIdx.x, lane = tid & 63, wave = tid >> 6;
    int wr = (wave >> 1) * 64, wc = (wave & 1) * 64;
    int m16 = lane & 15, kg8 = (lane >> 4) * 8;
    const unsigned short* Ap = A + (size_t)(bm * 128 + (tid >> 2)) * lda + (tid & 3) * 8;
    const unsigned short* Bp = B + (size_t)(bn * 128 + (tid >> 2)) * ldb + (tid & 3) * 8;
    unsigned short* Asd = &As[tid >> 2][(tid & 3) * 8];   // = As base + tid*16B (lane-linear)
    unsigned short* Bsd = &Bs[tid >> 2][(tid & 3) * 8];
    size_t a64 = (size_t)64 * lda, b64 = (size_t)64 * ldb;
    frag_cd acc[4][4] = {};
    for (int k0 = 0; k0 < K; k0 += 32) {
        gl_lds16(Ap + k0,       Asd);
        gl_lds16(Ap + a64 + k0, Asd + 64 * 32);
        gl_lds16(Bp + k0,       Bsd);
        gl_lds16(Bp + b64 + k0, Bsd + 64 * 32);
        __syncthreads();
        frag_ab af[4], bf[4];
        #pragma unroll
        for (int i = 0; i < 4; ++i) af[i] = *(const frag_ab*)&As[wr + i * 16 + m16][kg8];
        #pragma unroll
        for (int i = 0; i < 4; ++i) bf[i] = *(const frag_ab*)&Bs[wc + i * 16 + m16][kg8];
        #pragma unroll
        for (int mt = 0; mt < 4; ++mt)
            #pragma unroll
            for (int nt = 0; nt < 4; ++nt)
                acc[mt][nt] = __builtin_amdgcn_mfma_f32_16x16x32_bf16(af[mt], bf[nt], acc[mt][nt], 0, 0, 0);
        __syncthreads();
    }
    #pragma unroll
    for (int mt = 0; mt < 4; ++mt) {
        int r0 = bm * 128 + wr + mt * 16 + (lane >> 4) * 4;
        #pragma unroll
        for (int nt = 0; nt < 4; ++nt) {
            int cc = bn * 128 + wc + nt * 16 + m16;
            #pragma unroll
            for (int i = 0; i < 4; ++i)
                C[(size_t)(r0 + i) * ldc + cc] = acc[mt][nt][i];
        }
    }
}

// ---------------- fused recurrence helpers ----------------
// gates GEMM, K=512: acc over 16 k-tiles; A rows = 16 LDS-resident W rows, B rows = batch.
static __device__ __forceinline__ void gemm_gates_512(const unsigned short (*Ws)[520],
                                                      const unsigned short* __restrict__ hb,
                                                      float (*gb)[132], int wave, int lane) {
    int m16 = lane & 15, kg8 = (lane >> 4) * 8;
    frag_cd a0 = {}, a1 = {};
    const unsigned short* r0 = hb + (size_t)(wave * 32 + m16) * EE + kg8;
    const unsigned short* r1 = r0 + 16 * EE;
    #pragma unroll
    for (int kt = 0; kt < 16; ++kt) {
        frag_ab af = *(const frag_ab*)&Ws[m16][kt * 32 + kg8];
        frag_ab b0 = *(const frag_ab*)(r0 + kt * 32);
        frag_ab b1 = *(const frag_ab*)(r1 + kt * 32);
        a0 = __builtin_amdgcn_mfma_f32_16x16x32_bf16(af, b0, a0, 0, 0, 0);
        a1 = __builtin_amdgcn_mfma_f32_16x16x32_bf16(af, b1, a1, 0, 0, 0);
    }
    int er = (lane >> 4) * 4;
    #pragma unroll
    for (int i = 0; i < 4; ++i) {
        gb[er + i][wave * 32 + m16]      = a0[i];
        gb[er + i][wave * 32 + 16 + m16] = a1[i];
    }
}

// gates GEMM, K=1024: cols 0..511 vs ha, cols 512..1023 vs hb2.
static __device__ __forceinline__ void gemm_gates_1024(const unsigned short (*Ws)[1032],
                                                       const unsigned short* __restrict__ ha,
                                                       const unsigned short* __restrict__ hb2,
                                                       float (*gb)[132], int wave, int lane) {
    int m16 = lane & 15, kg8 = (lane >> 4) * 8;
    frag_cd a0 = {}, a1 = {};
    const unsigned short* r0 = ha + (size_t)(wave * 32 + m16) * EE + kg8;
    const unsigned short* r1 = r0 + 16 * EE;
    #pragma unroll
    for (int kt = 0; kt < 16; ++kt) {
        frag_ab af = *(const frag_ab*)&Ws[m16][kt * 32 + kg8];
        frag_ab b0 = *(const frag_ab*)(r0 + kt * 32);
        frag_ab b1 = *(const frag_ab*)(r1 + kt * 32);
        a0 = __builtin_amdgcn_mfma_f32_16x16x32_bf16(af, b0, a0, 0, 0, 0);
        a1 = __builtin_amdgcn_mfma_f32_16x16x32_bf16(af, b1, a1, 0, 0, 0);
    }
    const unsigned short* s0 = hb2 + (size_t)(wave * 32 + m16) * EE + kg8;
    const unsigned short* s1 = s0 + 16 * EE;
    #pragma unroll
    for (int kt = 0; kt < 16; ++kt) {
        frag_ab af = *(const frag_ab*)&Ws[m16][512 + kt * 32 + kg8];
        frag_ab b0 = *(const frag_ab*)(s0 + kt * 32);
        frag_ab b1 = *(const frag_ab*)(s1 + kt * 32);
        a0 = __builtin_amdgcn_mfma_f32_16x16x32_bf16(af, b0, a0, 0, 0, 0);
        a1 = __builtin_amdgcn_mfma_f32_16x16x32_bf16(af, b1, a1, 0, 0, 0);
    }
    int er = (lane >> 4) * 4;
    #pragma unroll
    for (int i = 0; i < 4; ++i) {
        gb[er + i][wave * 32 + m16]      = a0[i];
        gb[er + i][wave * 32 + 16 + m16] = a1[i];
    }
}

static __device__ __forceinline__ void pw_item(float gi, float gf, float gg, float go,
                                               float& c, unsigned short* h) {
    float cn = sigf(gf) * c + sigf(gi) * tanhf_(gg);
    c = cn;
    *h = f2bf_rne(sigf(go) * tanhf_(cn));
}

// ---------------- persistent fused recurrence: 80 enc + 29 dec steps, one launch ----------------
// block k owns e-lanes [4k,4k+4) x 4 gates = 16 rows of W1 (whh1) and W2 (wcat2), LDS-resident.
// c1/c2 slices live in registers for the whole sequence. h1/h2 ping-pong in global bf16.
__global__ __launch_bounds__(256, 1) void fused_seq(
        const unsigned short* __restrict__ W1,     // whh1_bf [2048][512]
        const unsigned short* __restrict__ W2,     // wcat2_bf [2048][1024]
        const unsigned short* __restrict__ Wout,   // [6016][512]
        const float* __restrict__ bias1, const float* __restrict__ bias2,
        const float* __restrict__ b_out,
        const float* __restrict__ P_enc,           // [(b*80+t)][2048]
        const float* __restrict__ P_dec,           // [(b*29+t)][2048]
        const int* __restrict__ labels,
        unsigned short* h1a, unsigned short* h1b,
        unsigned short* h2a, unsigned short* h2b,
        float* __restrict__ logits,                // [128][6016]
        unsigned int* barcnt, float* out) {
    __shared__ unsigned short W1s[16][520];        // +8 pad: 2-way bank alias only (free)
    __shared__ unsigned short W2s[16][1032];
    __shared__ float gbuf[16][132];
    __shared__ float red[256];

    int tid = threadIdx.x, lane = tid & 63, wave = tid >> 6;
    int blk = blockIdx.x;
    int e0 = blk * 4;
    int jj = tid & 3, brow = tid >> 2;             // pointwise item (e-lane jj, batches brow/brow+64)
    int m16 = lane & 15, kg8 = (lane >> 4) * 8;

    // one-time W load into LDS (local row r = gate*4 + j  <->  W row gate*512 + e0 + j)
    #pragma unroll
    for (int i = 0; i < 4; ++i) {
        int idx = i * 256 + tid;                   // 1024 x uint4 for W1 (16 x 512)
        int r = idx >> 6, c8 = (idx & 63) * 8;
        *(uint4*)&W1s[r][c8] = *(const uint4*)(W1 + (size_t)((r >> 2) * EE + e0 + (r & 3)) * EE + c8);
    }
    #pragma unroll
    for (int i = 0; i < 8; ++i) {
        int idx = i * 256 + tid;                   // 2048 x uint4 for W2 (16 x 1024)
        int r = idx >> 7, c8 = (idx & 127) * 8;
        *(uint4*)&W2s[r][c8] = *(const uint4*)(W2 + (size_t)((r >> 2) * EE + e0 + (r & 3)) * 1024 + c8);
    }
    float bs1[4], bs2[4];
    #pragma unroll
    for (int g = 0; g < 4; ++g) {
        bs1[g] = bias1[g * EE + e0 + jj];
        bs2[g] = bias2[g * EE + e0 + jj];
    }
    float c1r0 = 0.f, c1r1 = 0.f, c2r0 = 0.f, c2r1 = 0.f;
    unsigned short *h1p = h1a, *h1c = h1b, *h2p = h2a, *h2c = h2b;
    unsigned int bars = 0;
    __syncthreads();

    // ---------------- encoder: 80 steps, 2 grid barriers each ----------------
    for (int t = 0; t < TFRM; ++t) {
        float pv0[4], pv1[4];                      // prefetch P_enc before the GEMM hides L3 latency
        {
            const float* pA = P_enc + ((size_t)(brow * TFRM + t)) * 2048 + e0 + jj;
            const float* pB = P_enc + ((size_t)((brow + 64) * TFRM + t)) * 2048 + e0 + jj;
            #pragma unroll
            for (int g = 0; g < 4; ++g) { pv0[g] = pA[g * EE]; pv1[g] = pB[g * EE]; }
        }
        gemm_gates_512(W1s, h1p, gbuf, wave, lane);
        __syncthreads();
        pw_item(gbuf[jj][brow] + bs1[0] + pv0[0],      gbuf[4 + jj][brow] + bs1[1] + pv0[1],
                gbuf[8 + jj][brow] + bs1[2] + pv0[2],  gbuf[12 + jj][brow] + bs1[3] + pv0[3],
                c1r0, &h1c[(size_t)brow * EE + e0 + jj]);
        pw_item(gbuf[jj][brow + 64] + bs1[0] + pv1[0],     gbuf[4 + jj][brow + 64] + bs1[1] + pv1[1],
                gbuf[8 + jj][brow + 64] + bs1[2] + pv1[2], gbuf[12 + jj][brow + 64] + bs1[3] + pv1[3],
                c1r1, &h1c[(size_t)(brow + 64) * EE + e0 + jj]);
        bars++; gridbar(barcnt, bars * NBLK);

        gemm_gates_1024(W2s, h1c, h2p, gbuf, wave, lane);
        __syncthreads();
        pw_item(gbuf[jj][brow] + bs2[0],      gbuf[4 + jj][brow] + bs2[1],
                gbuf[8 + jj][brow] + bs2[2],  gbuf[12 + jj][brow] + bs2[3],
                c2r0, &h2c[(size_t)brow * EE + e0 + jj]);
        pw_item(gbuf[jj][brow + 64] + bs2[0],     gbuf[4 + jj][brow + 64] + bs2[1],
                gbuf[8 + jj][brow + 64] + bs2[2], gbuf[12 + jj][brow + 64] + bs2[3],
                c2r1, &h2c[(size_t)(brow + 64) * EE + e0 + jj]);
        bars++; gridbar(barcnt, bars * NBLK);

        { unsigned short* tmp = h1p; h1p = h1c; h1c = tmp; }
        { unsigned short* tmp = h2p; h2p = h2c; h2c = tmp; }
    }

    // ---------------- decoder: 29 steps, 3 grid barriers each ----------------
    for (int t = 0; t < DECL - 1; ++t) {
        gemm_gates_512(W1s, h1p, gbuf, wave, lane);     // lstm1 input is zeros -> no P
        __syncthreads();
        pw_item(gbuf[jj][brow] + bs1[0],      gbuf[4 + jj][brow] + bs1[1],
                gbuf[8 + jj][brow] + bs1[2],  gbuf[12 + jj][brow] + bs1[3],
                c1r0, &h1c[(size_t)brow * EE + e0 + jj]);
        pw_item(gbuf[jj][brow + 64] + bs1[0],     gbuf[4 + jj][brow + 64] + bs1[1],
                gbuf[8 + jj][brow + 64] + bs1[2], gbuf[12 + jj][brow + 64] + bs1[3],
                c1r1, &h1c[(size_t)(brow + 64) * EE + e0 + jj]);
        bars++; gridbar(barcnt, bars * NBLK);

        float pv0[4], pv1[4];
        {
            const float* pA = P_dec + ((size_t)(brow * 29 + t)) * 2048 + e0 + jj;
            const float* pB = P_dec + ((size_t)((brow + 64) * 29 + t)) * 2048 + e0 + jj;
            #pragma unroll
            for (int g = 0; g < 4; ++g) { pv0[g] = pA[g * EE]; pv1[g] = pB[g * EE]; }
        }
        gemm_gates_1024(W2s, h1c, h2p, gbuf, wave, lane);
        __syncthreads();
        pw_item(gbuf[jj][brow] + bs2[0] + pv0[0],      gbuf[4 + jj][brow] + bs2[1] + pv0[1],
                gbuf[8 + jj][brow] + bs2[2] + pv0[2],  gbuf[12 + jj][brow] + bs2[3] + pv0[3],
                c2r0, &h2c[(size_t)brow * EE + e0 + jj]);
        pw_item(gbuf[jj][brow + 64] + bs2[0] + pv1[0],     gbuf[4 + jj][brow + 64] + bs2[1] + pv1[1],
                gbuf[8 + jj][brow + 64] + bs2[2] + pv1[2], gbuf[12 + jj][brow + 64] + bs2[3] + pv1[3],
                c2r1, &h2c[(size_t)(brow + 64) * EE + e0 + jj]);
        bars++; gridbar(barcnt, bars * NBLK);

        // logits[b][v] = h2 @ wout^T + b_out : block handles vocab tiles vt = blk, blk+128, ...
        for (int vt = blk; vt < VPAD / 16; vt += NBLK) {
            frag_cd a0 = {}, a1 = {};
            const unsigned short* wp = Wout + (size_t)(vt * 16 + m16) * EE + kg8;
            const unsigned short* r0 = h2c + (size_t)(wave * 32 + m16) * EE + kg8;
            const unsigned short* r1 = r0 + 16 * EE;
            #pragma unroll
            for (int kt = 0; kt < 16; ++kt) {
                frag_ab af = *(const frag_ab*)(wp + kt * 32);
                frag_ab b0 = *(const frag_ab*)(r0 + kt * 32);
                frag_ab b1 = *(const frag_ab*)(r1 + kt * 32);
                a0 = __builtin_amdgcn_mfma_f32_16x16x32_bf16(af, b0, a0, 0, 0, 0);
                a1 = __builtin_amdgcn_mfma_f32_16x16x32_bf16(af, b1, a1, 0, 0, 0);
            }
            int v0 = vt * 16 + (lane >> 4) * 4;
            float bb0 = (v0     < VV) ? b_out[v0]     : 0.f;
            float bb1 = (v0 + 1 < VV) ? b_out[v0 + 1] : 0.f;
            float bb2 = (v0 + 2 < VV) ? b_out[v0 + 2] : 0.f;
            float bb3 = (v0 + 3 < VV) ? b_out[v0 + 3] : 0.f;
            int br0 = wave * 32 + m16;
            *(float4*)&logits[(size_t)br0 * VPAD + v0] =
                make_float4(a0[0] + bb0, a0[1] + bb1, a0[2] + bb2, a0[3] + bb3);
            *(float4*)&logits[(size_t)(br0 + 16) * VPAD + v0] =
                make_float4(a1[0] + bb0, a1[1] + bb1, a1[2] + bb2, a1[3] + bb3);
        }
        bars++; gridbar(barcnt, bars * NBLK);

        // loss for batch row b = blk (runs before next barrier -> safely precedes logits overwrite)
        {
            const float* lg = logits + (size_t)blk * VPAD;
            float mx = -1e30f;
            for (int v = tid; v < VV; v += 256) mx = fmaxf(mx, lg[v]);
            red[tid] = mx; __syncthreads();
            for (int s = 128; s; s >>= 1) {
                if (tid < s) red[tid] = fmaxf(red[tid], red[tid + s]);
                __syncthreads();
            }
            mx = red[0]; __syncthreads();
            float sm = 0.f;
            for (int v = tid; v < VV; v += 256) sm += __expf(lg[v] - mx);
            red[tid] = sm; __syncthreads();
            for (int s = 128; s; s >>= 1) {
                if (tid < s) red[tid] += red[tid + s];
                __syncthreads();
            }
            if (tid == 0) {
                int lab = labels[blk * DECL + t + 1];
                atomicAdd(out, (mx + __logf(red[0]) - lg[lab]) * (1.0f / BB));
            }
            __syncthreads();
        }

        { unsigned short* tmp = h1p; h1p = h1c; h1c = tmp; }
        { unsigned short* tmp = h2p; h2p = h2c; h2c = tmp; }
    }
}

extern "C" void kernel_launch(void* const* d_in, const int* in_sizes, int n_in,
                              void* d_out, int out_size, void* d_ws, size_t ws_size,
                              hipStream_t stream) {
    const float* feat    = (const float*)d_in[0];
    const float* caption = (const float*)d_in[1];
    const float* onehot  = (const float*)d_in[2];
    const float* w_ih1   = (const float*)d_in[3];
    const float* w_hh1   = (const float*)d_in[4];
    const float* b_ih1   = (const float*)d_in[5];
    const float* b_hh1   = (const float*)d_in[6];
    const float* w_ih2   = (const float*)d_in[7];
    const float* w_hh2   = (const float*)d_in[8];
    const float* b_ih2   = (const float*)d_in[9];
    const float* b_hh2   = (const float*)d_in[10];
    const float* w_out   = (const float*)d_in[11];
    const float* b_out   = (const float*)d_in[12];
    float* out = (float*)d_out;

    char* ws = (char*)d_ws;
    size_t off = 0;
    auto alloc = [&](size_t bytes) -> char* {
        char* p = ws + off;
        off = (off + bytes + 255) & ~(size_t)255;
        return p;
    };
    unsigned short* feat_bf  = (unsigned short*)alloc((size_t)BB * TFRM * FEATD * 2);  // 83.9 MB
    unsigned short* wih1_bf  = (unsigned short*)alloc((size_t)2048 * FEATD * 2);       // 16.8 MB
    unsigned short* wih2_bf  = (unsigned short*)alloc((size_t)2048 * 1024 * 2);        // 4.2 MB
    unsigned short* whh1_bf  = (unsigned short*)alloc((size_t)2048 * EE * 2);          // 2.1 MB
    unsigned short* wcat2_bf = (unsigned short*)alloc((size_t)2048 * 1024 * 2);        // 4.2 MB
    unsigned short* wout_bf  = (unsigned short*)alloc((size_t)VPAD * EE * 2);          // 6.2 MB
    float* P_enc = (float*)alloc((size_t)BB * TFRM * 2048 * 4);                        // 83.9 MB
    float* P_dec = (float*)alloc((size_t)BB * 29 * 2048 * 4);                          // 30.4 MB
    unsigned short* xdec_bf = (unsigned short*)alloc((size_t)BB * 29 * EE * 2);        // 3.8 MB
    unsigned short* h1a = (unsigned short*)alloc((size_t)BB * EE * 2);
    unsigned short* h1b = (unsigned short*)alloc((size_t)BB * EE * 2);
    unsigned short* h2a = (unsigned short*)alloc((size_t)BB * EE * 2);
    unsigned short* h2b = (unsigned short*)alloc((size_t)BB * EE * 2);
    float* logits = (float*)alloc((size_t)BB * VPAD * 4);                              // 3.1 MB
    float* bias1 = (float*)alloc(2048 * 4);
    float* bias2 = (float*)alloc(2048 * 4);
    int* labels = (int*)alloc((size_t)BB * DECL * 4);
    unsigned int* barcnt = (unsigned int*)alloc(256);
    if (off > ws_size) return;  // fail loudly (out stays poisoned)

    init_zero<<<128, 256, 0, stream>>>((unsigned int*)h1a, (unsigned int*)h1b,
                                       (unsigned int*)h2a, (unsigned int*)h2b, out, barcnt);
    f2bf<<<40960, 256, 0, stream>>>(feat, feat_bf, BB * TFRM * FEATD / 4);
    f2bf<<<8192, 256, 0, stream>>>(w_ih1, wih1_bf, 2048 * FEATD / 4);
    f2bf<<<2048, 256, 0, stream>>>(w_ih2, wih2_bf, 2048 * 1024 / 4);
    f2bf<<<1024, 256, 0, stream>>>(w_hh1, whh1_bf, 2048 * EE / 4);
    build_wcat2<<<2048, 256, 0, stream>>>(w_ih2, w_hh2, wcat2_bf, 2048 * 1024 / 4);
    wout_pad<<<3008, 256, 0, stream>>>(w_out, wout_bf, VPAD * EE / 4);
    xdec_gather<<<1856, 256, 0, stream>>>(caption, xdec_bf, BB * 29 * EE / 4);
    bias_sum<<<8, 256, 0, stream>>>(b_ih1, b_hh1, b_ih2, b_hh2, bias1, bias2);
    argmax_k<<<BB * DECL, 64, 0, stream>>>(onehot, labels);

    // P_enc[(b*80+t), 2048] = feat @ w_ih1^T   (M=10240, N=2048, K=4096)
    gemm128<<<80 * 16, 256, 0, stream>>>(feat_bf, FEATD, wih1_bf, FEATD, P_enc, 2048, FEATD, 16);
    // P_dec[(b*29+t), 2048] = x_word @ w_ih2[:, :512]^T   (M=3712, N=2048, K=512, ldb=1024)
    gemm128<<<29 * 16, 256, 0, stream>>>(xdec_bf, EE, wih2_bf, 1024, P_dec, 2048, EE, 16);

    // whole recurrence (80 enc + 29 dec steps incl. logits+loss) in one persistent launch
    fused_seq<<<NBLK, 256, 0, stream>>>(whh1_bf, wcat2_bf, wout_bf, bias1, bias2, b_out,
                                        P_enc, P_dec, labels,
                                        h1a, h1b, h2a, h2b, logits, barcnt, out);
}

// Round 2
// 3121.062 us; speedup vs baseline: 1.7162x; 1.7162x over previous
//
#include <hip/hip_runtime.h>
#include <cstdint>
#include <cstddef>

#define BB    128
#define TFRM  80
#define DECL  30
#define EE    512
#define FEATD 4096
#define VV    6000
#define VPAD  6016
#define NBLK  128
#define HSLOT (128 * 512)   // one h2 time slot (ushorts)

using frag_ab = __attribute__((ext_vector_type(8))) short;
using frag_cd = __attribute__((ext_vector_type(4))) float;

static __device__ __forceinline__ float sigf(float x)  { return 1.0f / (1.0f + __expf(-x)); }
static __device__ __forceinline__ float tanhf_(float x){ float e = __expf(2.0f * x); return 1.0f - 2.0f / (e + 1.0f); }
static __device__ __forceinline__ unsigned short f2bf_rne(float x) {
    unsigned int u = __float_as_uint(x);
    u += 0x7fffu + ((u >> 16) & 1u);
    return (unsigned short)(u >> 16);
}

// async global->LDS, 16B per lane. LDS dest must be wave-uniform base + lane*16.
static __device__ __forceinline__ void gl_lds16(const unsigned short* g, unsigned short* l) {
    __builtin_amdgcn_global_load_lds(
        (const __attribute__((address_space(1))) unsigned int*)g,
        (__attribute__((address_space(3))) unsigned int*)l, 16, 0, 0);
}

// ---- flag-array grid barrier: no same-line RMW storm ----
// arrival: one system-scope (write-through) store per block to its own flag.
// detect: threads 0..127 each spin on one flag. acquire: single buffer_inv.
static __device__ __forceinline__ void flagbar(unsigned int* flags, unsigned int epoch) {
    __syncthreads();                       // drains vmcnt: all h system-stores complete
    int t = threadIdx.x;
    if (t == 0)
        __hip_atomic_store(&flags[blockIdx.x], epoch, __ATOMIC_RELEASE, __HIP_MEMORY_SCOPE_SYSTEM);
    if (t < NBLK) {
        while (__hip_atomic_load(&flags[t], __ATOMIC_RELAXED, __HIP_MEMORY_SCOPE_SYSTEM) < epoch)
            __builtin_amdgcn_s_sleep(2);
    }
    __builtin_amdgcn_fence(__ATOMIC_ACQUIRE, "agent");   // buffer_inv: drop stale L1/L2
    __syncthreads();
}

// ---------------- init: zero h buffers, h2 slot0, flags, out ----------------
__global__ void init_zero(unsigned int* h1a, unsigned int* h1b, unsigned int* htmp,
                          unsigned int* h2slot0, unsigned int* flags, float* out) {
    int i = blockIdx.x * blockDim.x + threadIdx.x;   // 32768 threads
    h1a[i] = 0u; h1b[i] = 0u; htmp[i] = 0u; h2slot0[i] = 0u;
    if (i < NBLK) flags[i] = 0u;
    if (i == 0) out[0] = 0.f;
}

// ---------------- fp32 -> bf16 (RNE), x4 ----------------
__global__ void f2bf(const float* __restrict__ src, unsigned short* __restrict__ dst, int n4) {
    int i = blockIdx.x * blockDim.x + threadIdx.x;
    if (i >= n4) return;
    float4 v = ((const float4*)src)[i];
    ushort4 o;
    o.x = f2bf_rne(v.x); o.y = f2bf_rne(v.y); o.z = f2bf_rne(v.z); o.w = f2bf_rne(v.w);
    ((ushort4*)dst)[i] = o;
}

// ---------------- build Wcat2 [2048,1024] bf16: cols 0..511 = w_ih2[:,512:], cols 512.. = w_hh2 ----------------
__global__ void build_wcat2(const float* __restrict__ w_ih2, const float* __restrict__ w_hh2,
                            unsigned short* __restrict__ dst, int n4) {
    int i = blockIdx.x * blockDim.x + threadIdx.x;   // n4 = 2048*1024/4
    if (i >= n4) return;
    int r  = i >> 8;              // /256
    int c  = (i & 255) * 4;
    const float* src = (c < 512) ? (w_ih2 + (size_t)r * 1024 + 512 + c)
                                 : (w_hh2 + (size_t)r * 512 + (c - 512));
    float4 v = *(const float4*)src;
    ushort4 o;
    o.x = f2bf_rne(v.x); o.y = f2bf_rne(v.y); o.z = f2bf_rne(v.z); o.w = f2bf_rne(v.w);
    ((ushort4*)dst)[i] = o;
}

// ---------------- w_out -> bf16 padded to 6016 rows (pad rows zero) ----------------
__global__ void wout_pad(const float* __restrict__ w_out, unsigned short* __restrict__ dst, int n4) {
    int i = blockIdx.x * blockDim.x + threadIdx.x;   // n4 = 6016*512/4
    if (i >= n4) return;
    int r = i >> 7;               // /128
    int c = (i & 127) * 4;
    ushort4 o;
    if (r < VV) {
        float4 v = *(const float4*)(w_out + (size_t)r * EE + c);
        o.x = f2bf_rne(v.x); o.y = f2bf_rne(v.y); o.z = f2bf_rne(v.z); o.w = f2bf_rne(v.w);
    } else {
        o.x = 0; o.y = 0; o.z = 0; o.w = 0;
    }
    ((ushort4*)dst)[i] = o;
}

// ---------------- gather decoder word inputs: rows r = b*29+t from caption[b][t][:] (t<29), bf16 ----------------
__global__ void xdec_gather(const float* __restrict__ cap, unsigned short* __restrict__ dst, int n4) {
    int i = blockIdx.x * blockDim.x + threadIdx.x;   // n4 = 3712*512/4
    if (i >= n4) return;
    int row = i >> 7;             // /128
    int c   = (i & 127) * 4;
    int b = row / 29, t = row - b * 29;
    float4 v = *(const float4*)(cap + (size_t)(b * DECL + t) * EE + c);
    ushort4 o;
    o.x = f2bf_rne(v.x); o.y = f2bf_rne(v.y); o.z = f2bf_rne(v.z); o.w = f2bf_rne(v.w);
    ((ushort4*)dst)[i] = o;
}

// ---------------- bias sums ----------------
__global__ void bias_sum(const float* b_ih1, const float* b_hh1, const float* b_ih2, const float* b_hh2,
                         float* bs1, float* bs2) {
    int i = blockIdx.x * blockDim.x + threadIdx.x;   // 2048
    bs1[i] = b_ih1[i] + b_hh1[i];
    bs2[i] = b_ih2[i] + b_hh2[i];
}

// ---------------- argmax over vocab (first-index ties) ----------------
__global__ void argmax_k(const float* __restrict__ oh, int* __restrict__ labels) {
    int row = blockIdx.x;                       // b*DECL + t
    const float* p = oh + (size_t)row * VV;
    int lane = threadIdx.x;
    float best = -1e30f; int bi = 0x7fffffff;
    for (int v = lane; v < VV; v += 64) {
        float x = p[v];
        if (x > best) { best = x; bi = v; }
    }
    for (int off = 32; off; off >>= 1) {
        float ob = __shfl_down(best, off);
        int   oi = __shfl_down(bi,   off);
        if (ob > best || (ob == best && oi < bi)) { best = ob; bi = oi; }
    }
    if (lane == 0) labels[row] = bi;
}

// ---------------- 128x128 bf16 NT GEMM (m97 structure: BK=32, global_load_lds w16) ----------------
// C[M,N](fp32,ldc) = A[M,K](lda) @ B[N,K](ldb)^T ; M%128==0, N%128==0, K%32==0
__global__ __launch_bounds__(256) void gemm128(const unsigned short* __restrict__ A, int lda,
                                               const unsigned short* __restrict__ B, int ldb,
                                               float* __restrict__ C, int ldc,
                                               int K, int ntn) {
    __shared__ unsigned short As[128][32];
    __shared__ unsigned short Bs[128][32];
    int bm = blockIdx.x / ntn, bn = blockIdx.x % ntn;
    int tid = threadIdx.x, lane = tid & 63, wave = tid >> 6;
    int wr = (wave >> 1) * 64, wc = (wave & 1) * 64;
    int m16 = lane & 15, kg8 = (lane >> 4) * 8;
    const unsigned short* Ap = A + (size_t)(bm * 128 + (tid >> 2)) * lda + (tid & 3) * 8;
    const unsigned short* Bp = B + (size_t)(bn * 128 + (tid >> 2)) * ldb + (tid & 3) * 8;
    unsigned short* Asd = &As[tid >> 2][(tid & 3) * 8];   // = As base + tid*16B (lane-linear)
    unsigned short* Bsd = &Bs[tid >> 2][(tid & 3) * 8];
    size_t a64 = (size_t)64 * lda, b64 = (size_t)64 * ldb;
    frag_cd acc[4][4] = {};
    for (int k0 = 0; k0 < K; k0 += 32) {
        gl_lds16(Ap + k0,       Asd);
        gl_lds16(Ap + a64 + k0, Asd + 64 * 32);
        gl_lds16(Bp + k0,       Bsd);
        gl_lds16(Bp + b64 + k0, Bsd + 64 * 32);
        __syncthreads();
        frag_ab af[4], bf[4];
        #pragma unroll
        for (int i = 0; i < 4; ++i) af[i] = *(const frag_ab*)&As[wr + i * 16 + m16][kg8];
        #pragma unroll
        for (int i = 0; i < 4; ++i) bf[i] = *(const frag_ab*)&Bs[wc + i * 16 + m16][kg8];
        #pragma unroll
        for (int mt = 0; mt < 4; ++mt)
            #pragma unroll
            for (int nt = 0; nt < 4; ++nt)
                acc[mt][nt] = __builtin_amdgcn_mfma_f32_16x16x32_bf16(af[mt], bf[nt], acc[mt][nt], 0, 0, 0);
        __syncthreads();
    }
    #pragma unroll
    for (int mt = 0; mt < 4; ++mt) {
        int r0 = bm * 128 + wr + mt * 16 + (lane >> 4) * 4;
        #pragma unroll
        for (int nt = 0; nt < 4; ++nt) {
            int cc = bn * 128 + wc + nt * 16 + m16;
            #pragma unroll
            for (int i = 0; i < 4; ++i)
                C[(size_t)(r0 + i) * ldc + cc] = acc[mt][nt][i];
        }
    }
}

// ---------------- fused recurrence helpers ----------------
static __device__ __forceinline__ void gemm_gates_512(const unsigned short (*Ws)[520],
                                                      const unsigned short* __restrict__ hb,
                                                      float (*gb)[132], int wave, int lane) {
    int m16 = lane & 15, kg8 = (lane >> 4) * 8;
    frag_cd a0 = {}, a1 = {};
    const unsigned short* r0 = hb + (size_t)(wave * 32 + m16) * EE + kg8;
    const unsigned short* r1 = r0 + 16 * EE;
    #pragma unroll
    for (int kt = 0; kt < 16; ++kt) {
        frag_ab af = *(const frag_ab*)&Ws[m16][kt * 32 + kg8];
        frag_ab b0 = *(const frag_ab*)(r0 + kt * 32);
        frag_ab b1 = *(const frag_ab*)(r1 + kt * 32);
        a0 = __builtin_amdgcn_mfma_f32_16x16x32_bf16(af, b0, a0, 0, 0, 0);
        a1 = __builtin_amdgcn_mfma_f32_16x16x32_bf16(af, b1, a1, 0, 0, 0);
    }
    int er = (lane >> 4) * 4;
    #pragma unroll
    for (int i = 0; i < 4; ++i) {
        gb[er + i][wave * 32 + m16]      = a0[i];
        gb[er + i][wave * 32 + 16 + m16] = a1[i];
    }
}

static __device__ __forceinline__ void gemm_gates_1024(const unsigned short (*Ws)[1032],
                                                       const unsigned short* __restrict__ ha,
                                                       const unsigned short* __restrict__ hb2,
                                                       float (*gb)[132], int wave, int lane) {
    int m16 = lane & 15, kg8 = (lane >> 4) * 8;
    frag_cd a0 = {}, a1 = {};
    const unsigned short* r0 = ha + (size_t)(wave * 32 + m16) * EE + kg8;
    const unsigned short* r1 = r0 + 16 * EE;
    #pragma unroll
    for (int kt = 0; kt < 16; ++kt) {
        frag_ab af = *(const frag_ab*)&Ws[m16][kt * 32 + kg8];
        frag_ab b0 = *(const frag_ab*)(r0 + kt * 32);
        frag_ab b1 = *(const frag_ab*)(r1 + kt * 32);
        a0 = __builtin_amdgcn_mfma_f32_16x16x32_bf16(af, b0, a0, 0, 0, 0);
        a1 = __builtin_amdgcn_mfma_f32_16x16x32_bf16(af, b1, a1, 0, 0, 0);
    }
    const unsigned short* s0 = hb2 + (size_t)(wave * 32 + m16) * EE + kg8;
    const unsigned short* s1 = s0 + 16 * EE;
    #pragma unroll
    for (int kt = 0; kt < 16; ++kt) {
        frag_ab af = *(const frag_ab*)&Ws[m16][512 + kt * 32 + kg8];
        frag_ab b0 = *(const frag_ab*)(s0 + kt * 32);
        frag_ab b1 = *(const frag_ab*)(s1 + kt * 32);
        a0 = __builtin_amdgcn_mfma_f32_16x16x32_bf16(af, b0, a0, 0, 0, 0);
        a1 = __builtin_amdgcn_mfma_f32_16x16x32_bf16(af, b1, a1, 0, 0, 0);
    }
    int er = (lane >> 4) * 4;
    #pragma unroll
    for (int i = 0; i < 4; ++i) {
        gb[er + i][wave * 32 + m16]      = a0[i];
        gb[er + i][wave * 32 + 16 + m16] = a1[i];
    }
}

// pointwise cell update; h store is system-scope write-through (visible without wbl2)
static __device__ __forceinline__ void pw_item(float gi, float gf, float gg, float go,
                                               float& c, unsigned short* h) {
    float cn = sigf(gf) * c + sigf(gi) * tanhf_(gg);
    c = cn;
    unsigned short hv = f2bf_rne(sigf(go) * tanhf_(cn));
    __hip_atomic_store(h, hv, __ATOMIC_RELAXED, __HIP_MEMORY_SCOPE_SYSTEM);
}

// ---------------- persistent fused recurrence: 109 steps, pipelined G2(s-1) || G1(s) ----------------
// block k owns e-lanes [4k,4k+4) x 4 gates = 16 rows of W1 and W2, LDS-resident.
// c1/c2 slices in registers. 110 grid barriers total (flag-array barrier).
__global__ __launch_bounds__(256, 1) void fused_seq(
        const unsigned short* __restrict__ W1,     // whh1_bf [2048][512]
        const unsigned short* __restrict__ W2,     // wcat2_bf [2048][1024]
        const float* __restrict__ bias1, const float* __restrict__ bias2,
        const float* __restrict__ P_enc,           // [(b*80+t)][2048]
        const float* __restrict__ P_dec,           // [(b*29+t)][2048]
        unsigned short* __restrict__ h1a, unsigned short* __restrict__ h1b,
        unsigned short* __restrict__ htmp,         // encoder h2 scratch
        unsigned short* __restrict__ h2all,        // [30][128][512]; slot0 = enc final
        unsigned int* __restrict__ flags) {
    __shared__ unsigned short W1s[16][520];
    __shared__ unsigned short W2s[16][1032];
    __shared__ float gbuf[16][132];

    int tid = threadIdx.x, lane = tid & 63, wave = tid >> 6;
    int blk = blockIdx.x;
    int e0 = blk * 4;
    int jj = tid & 3, brow = tid >> 2;

    // one-time W load into LDS (local row r = gate*4 + j  <->  W row gate*512 + e0 + j)
    #pragma unroll
    for (int i = 0; i < 4; ++i) {
        int idx = i * 256 + tid;
        int r = idx >> 6, c8 = (idx & 63) * 8;
        *(uint4*)&W1s[r][c8] = *(const uint4*)(W1 + (size_t)((r >> 2) * EE + e0 + (r & 3)) * EE + c8);
    }
    #pragma unroll
    for (int i = 0; i < 8; ++i) {
        int idx = i * 256 + tid;
        int r = idx >> 7, c8 = (idx & 127) * 8;
        *(uint4*)&W2s[r][c8] = *(const uint4*)(W2 + (size_t)((r >> 2) * EE + e0 + (r & 3)) * 1024 + c8);
    }
    float bs1[4], bs2[4];
    #pragma unroll
    for (int g = 0; g < 4; ++g) {
        bs1[g] = bias1[g * EE + e0 + jj];
        bs2[g] = bias2[g * EE + e0 + jj];
    }
    float c1r0 = 0.f, c1r1 = 0.f, c2r0 = 0.f, c2r1 = 0.f;
    __syncthreads();

    // h1(s) lives in (s&1 ? h1a : h1b); h1(-1) = h1a (zeros)
    auto h1buf = [&](int s) -> unsigned short* { return (s & 1) ? h1a : h1b; };
    // encoder h2(s): s even -> htmp, s odd -> slot0 (s=79 ends in slot0 = h2all)
    auto h2wr = [&](int s) -> unsigned short* {
        if (s < 80) return (s & 1) ? h2all : htmp;
        return h2all + (size_t)(s - 79) * HSLOT;
    };
    auto h2rd = [&](int s) -> unsigned short* {   // = h2wr(s-1); h2(-1) = slot0 zeros
        if (s == 0) return h2all;
        if (s <= 80) return ((s - 1) & 1) ? h2all : htmp;
        return h2all + (size_t)(s - 80) * HSLOT;
    };

    auto do_G1 = [&](int s) {
        float pv0[4] = {0.f, 0.f, 0.f, 0.f}, pv1[4] = {0.f, 0.f, 0.f, 0.f};
        if (s < 80) {
            const float* pA = P_enc + ((size_t)(brow * TFRM + s)) * 2048 + e0 + jj;
            const float* pB = P_enc + ((size_t)((brow + 64) * TFRM + s)) * 2048 + e0 + jj;
            #pragma unroll
            for (int g = 0; g < 4; ++g) { pv0[g] = pA[g * EE]; pv1[g] = pB[g * EE]; }
        }
        gemm_gates_512(W1s, h1buf(s - 1), gbuf, wave, lane);
        __syncthreads();
        unsigned short* hc = h1buf(s);
        pw_item(gbuf[jj][brow] + bs1[0] + pv0[0],      gbuf[4 + jj][brow] + bs1[1] + pv0[1],
                gbuf[8 + jj][brow] + bs1[2] + pv0[2],  gbuf[12 + jj][brow] + bs1[3] + pv0[3],
                c1r0, &hc[(size_t)brow * EE + e0 + jj]);
        pw_item(gbuf[jj][brow + 64] + bs1[0] + pv1[0],     gbuf[4 + jj][brow + 64] + bs1[1] + pv1[1],
                gbuf[8 + jj][brow + 64] + bs1[2] + pv1[2], gbuf[12 + jj][brow + 64] + bs1[3] + pv1[3],
                c1r1, &hc[(size_t)(brow + 64) * EE + e0 + jj]);
    };

    auto do_G2 = [&](int s) {
        float pv0[4] = {0.f, 0.f, 0.f, 0.f}, pv1[4] = {0.f, 0.f, 0.f, 0.f};
        if (s >= 80) {
            int td = s - 80;
            const float* pA = P_dec + ((size_t)(brow * 29 + td)) * 2048 + e0 + jj;
            const float* pB = P_dec + ((size_t)((brow + 64) * 29 + td)) * 2048 + e0 + jj;
            #pragma unroll
            for (int g = 0; g < 4; ++g) { pv0[g] = pA[g * EE]; pv1[g] = pB[g * EE]; }
        }
        gemm_gates_1024(W2s, h1buf(s), h2rd(s), gbuf, wave, lane);
        __syncthreads();
        unsigned short* hc = h2wr(s);
        pw_item(gbuf[jj][brow] + bs2[0] + pv0[0],      gbuf[4 + jj][brow] + bs2[1] + pv0[1],
                gbuf[8 + jj][brow] + bs2[2] + pv0[2],  gbuf[12 + jj][brow] + bs2[3] + pv0[3],
                c2r0, &hc[(size_t)brow * EE + e0 + jj]);
        pw_item(gbuf[jj][brow + 64] + bs2[0] + pv1[0],     gbuf[4 + jj][brow + 64] + bs2[1] + pv1[1],
                gbuf[8 + jj][brow + 64] + bs2[2] + pv1[2], gbuf[12 + jj][brow + 64] + bs2[3] + pv1[3],
                c2r1, &hc[(size_t)(brow + 64) * EE + e0 + jj]);
    };

    unsigned int epoch = 0;
    do_G1(0);
    flagbar(flags, ++epoch);
    for (int s = 1; s <= 108; ++s) {
        do_G2(s - 1);
        __syncthreads();          // gbuf reuse guard
        do_G1(s);
        flagbar(flags, ++epoch);
    }
    do_G2(108);
}

// ---------------- loss over precomputed logits [3712, 6016] (bias added on the fly) ----------------
__global__ __launch_bounds__(256) void loss_rows_k(const float* __restrict__ logits,
                                                   const float* __restrict__ b_out,
                                                   const int* __restrict__ labels,
                                                   float* __restrict__ loss_rows) {
    __shared__ float red[256];
    int r = blockIdx.x;                 // t*128 + b
    int t = r >> 7, b = r & 127;
    const float* lg = logits + (size_t)r * VPAD;
    int tid = threadIdx.x;
    float mx = -1e30f;
    for (int v = tid; v < VV; v += 256) mx = fmaxf(mx, lg[v] + b_out[v]);
    red[tid] = mx; __syncthreads();
    for (int s = 128; s; s >>= 1) {
        if (tid < s) red[tid] = fmaxf(red[tid], red[tid + s]);
        __syncthreads();
    }
    mx = red[0]; __syncthreads();
    float sm = 0.f;
    for (int v = tid; v < VV; v += 256) sm += __expf(lg[v] + b_out[v] - mx);
    red[tid] = sm; __syncthreads();
    for (int s = 128; s; s >>= 1) {
        if (tid < s) red[tid] += red[tid + s];
        __syncthreads();
    }
    if (tid == 0) {
        int lab = labels[b * DECL + t + 1];
        loss_rows[r] = mx + __logf(red[0]) - (lg[lab] + b_out[lab]);
    }
}

__global__ void loss_final(const float* __restrict__ loss_rows, float* __restrict__ out) {
    __shared__ float red[256];
    int tid = threadIdx.x;
    float s = 0.f;
    for (int i = tid; i < 29 * BB; i += 256) s += loss_rows[i];
    red[tid] = s; __syncthreads();
    for (int st = 128; st; st >>= 1) {
        if (tid < st) red[tid] += red[tid + st];
        __syncthreads();
    }
    if (tid == 0) out[0] = red[0] * (1.0f / BB);
}

extern "C" void kernel_launch(void* const* d_in, const int* in_sizes, int n_in,
                              void* d_out, int out_size, void* d_ws, size_t ws_size,
                              hipStream_t stream) {
    const float* feat    = (const float*)d_in[0];
    const float* caption = (const float*)d_in[1];
    const float* onehot  = (const float*)d_in[2];
    const float* w_ih1   = (const float*)d_in[3];
    const float* w_hh1   = (const float*)d_in[4];
    const float* b_ih1   = (const float*)d_in[5];
    const float* b_hh1   = (const float*)d_in[6];
    const float* w_ih2   = (const float*)d_in[7];
    const float* w_hh2   = (const float*)d_in[8];
    const float* b_ih2   = (const float*)d_in[9];
    const float* b_hh2   = (const float*)d_in[10];
    const float* w_out   = (const float*)d_in[11];
    const float* b_out   = (const float*)d_in[12];
    float* out = (float*)d_out;

    char* ws = (char*)d_ws;
    size_t off = 0;
    auto alloc = [&](size_t bytes) -> char* {
        char* p = ws + off;
        off = (off + bytes + 255) & ~(size_t)255;
        return p;
    };
    // union region: feat_bf (83.9 MB, dead after P_enc gemm) / logits_all (89.3 MB, used after fused_seq)
    char* uni = alloc((size_t)3712 * VPAD * 4);
    unsigned short* feat_bf   = (unsigned short*)uni;
    float*          logits    = (float*)uni;
    unsigned short* wih1_bf  = (unsigned short*)alloc((size_t)2048 * FEATD * 2);       // 16.8 MB
    unsigned short* wih2_bf  = (unsigned short*)alloc((size_t)2048 * 1024 * 2);        // 4.2 MB
    unsigned short* whh1_bf  = (unsigned short*)alloc((size_t)2048 * EE * 2);          // 2.1 MB
    unsigned short* wcat2_bf = (unsigned short*)alloc((size_t)2048 * 1024 * 2);        // 4.2 MB
    unsigned short* wout_bf  = (unsigned short*)alloc((size_t)VPAD * EE * 2);          // 6.2 MB
    float* P_enc = (float*)alloc((size_t)BB * TFRM * 2048 * 4);                        // 83.9 MB
    float* P_dec = (float*)alloc((size_t)BB * 29 * 2048 * 4);                          // 30.4 MB
    unsigned short* xdec_bf = (unsigned short*)alloc((size_t)BB * 29 * EE * 2);        // 3.8 MB
    unsigned short* h1a  = (unsigned short*)alloc((size_t)BB * EE * 2);
    unsigned short* h1b  = (unsigned short*)alloc((size_t)BB * EE * 2);
    unsigned short* htmp = (unsigned short*)alloc((size_t)BB * EE * 2);
    unsigned short* h2all = (unsigned short*)alloc((size_t)30 * HSLOT * 2);            // 3.9 MB
    float* bias1 = (float*)alloc(2048 * 4);
    float* bias2 = (float*)alloc(2048 * 4);
    int* labels = (int*)alloc((size_t)BB * DECL * 4);
    float* loss_rows = (float*)alloc((size_t)29 * BB * 4);
    unsigned int* flags = (unsigned int*)alloc(NBLK * 4);
    if (off > ws_size) return;  // fail loudly (out stays poisoned)

    init_zero<<<128, 256, 0, stream>>>((unsigned int*)h1a, (unsigned int*)h1b,
                                       (unsigned int*)htmp, (unsigned int*)h2all, flags, out);
    f2bf<<<40960, 256, 0, stream>>>(feat, feat_bf, BB * TFRM * FEATD / 4);
    f2bf<<<8192, 256, 0, stream>>>(w_ih1, wih1_bf, 2048 * FEATD / 4);
    f2bf<<<2048, 256, 0, stream>>>(w_ih2, wih2_bf, 2048 * 1024 / 4);
    f2bf<<<1024, 256, 0, stream>>>(w_hh1, whh1_bf, 2048 * EE / 4);
    build_wcat2<<<2048, 256, 0, stream>>>(w_ih2, w_hh2, wcat2_bf, 2048 * 1024 / 4);
    wout_pad<<<3008, 256, 0, stream>>>(w_out, wout_bf, VPAD * EE / 4);
    xdec_gather<<<1856, 256, 0, stream>>>(caption, xdec_bf, BB * 29 * EE / 4);
    bias_sum<<<8, 256, 0, stream>>>(b_ih1, b_hh1, b_ih2, b_hh2, bias1, bias2);
    argmax_k<<<BB * DECL, 64, 0, stream>>>(onehot, labels);

    // P_enc[(b*80+t), 2048] = feat @ w_ih1^T   (M=10240, N=2048, K=4096)
    gemm128<<<80 * 16, 256, 0, stream>>>(feat_bf, FEATD, wih1_bf, FEATD, P_enc, 2048, FEATD, 16);
    // P_dec[(b*29+t), 2048] = x_word @ w_ih2[:, :512]^T   (M=3712, N=2048, K=512, ldb=1024)
    gemm128<<<29 * 16, 256, 0, stream>>>(xdec_bf, EE, wih2_bf, 1024, P_dec, 2048, EE, 16);

    // whole recurrence (109 steps) in one persistent launch; h2 decoder states -> h2all slots 1..29
    fused_seq<<<NBLK, 256, 0, stream>>>(whh1_bf, wcat2_bf, bias1, bias2,
                                        P_enc, P_dec, h1a, h1b, htmp, h2all, flags);

    // logits[(t*128+b), 6016] = h2all[slot t+1] @ wout^T   (M=3712, N=6016, K=512)
    gemm128<<<29 * 47, 256, 0, stream>>>(h2all + HSLOT, EE, wout_bf, EE, logits, VPAD, EE, 47);
    loss_rows_k<<<29 * BB, 256, 0, stream>>>(logits, b_out, labels, loss_rows);
    loss_final<<<1, 256, 0, stream>>>(loss_rows, out);
}